// Round 2
// baseline (492.391 us; speedup 1.0000x reference)
//
#include <hip/hip_runtime.h>
#include <cstdint>
#include <cstddef>

typedef __bf16 bf16_t;
typedef __bf16 bf16x8 __attribute__((ext_vector_type(8)));
typedef __bf16 bf16x4v __attribute__((ext_vector_type(4)));
typedef float f32x16 __attribute__((ext_vector_type(16)));

static __device__ __forceinline__ f32x16 mfma32(bf16x8 a, bf16x8 b, f32x16 c) {
  return __builtin_amdgcn_mfma_f32_32x32x16_bf16(a, b, c, 0, 0, 0);
}

#define CEXP_CONST 0.12754582f  // (1/sqrt(128)) * log2(e)

// ---------------------------------------------------------------------------
// Workspace layout (bytes):
//   [0, 768K)        Wt    bf16 [3][128][1024]
//   [1M, 9M)         Qp    bf16 [8][4096][128]
//   [9M, 17M)        Kp    bf16 [8][4096][128]
//   [17M, 25M)       Vt    bf16 [8][128][4096]
//   [32M, 64M)       Opart f32  [2*512][64][128]   (split-KV partials)
//   [64M, +256K)     Mpart f32  [2*512*64]
//   [64M+256K,+256K) Lpart f32  [2*512*64]
// ---------------------------------------------------------------------------

__global__ void wt_kernel(const float* __restrict__ Wq, const float* __restrict__ Wk,
                          const float* __restrict__ Wv, bf16_t* __restrict__ Wt) {
  int t = blockIdx.x * 256 + threadIdx.x;
  int tensor = t >> 17;
  int r = t & 131071;
  int kk = r >> 7, n = r & 127;
  const float* W = tensor == 0 ? Wq : (tensor == 1 ? Wk : Wv);
  Wt[(size_t)tensor * 131072 + (size_t)n * 1024 + kk] = (bf16_t)W[(size_t)kk * 128 + n];
}

// X[32768,1024]f32 @ W[1024,128] -> bf16. ty: 0=Q, 1=K (row-major), 2=V (transposed out).
__global__ __launch_bounds__(256, 2) void proj_kernel(
    const float* __restrict__ xq, const float* __restrict__ xk, const float* __restrict__ xv,
    const bf16_t* __restrict__ WtAll,
    bf16_t* __restrict__ Qp, bf16_t* __restrict__ Kp, bf16_t* __restrict__ Vt) {
  __shared__ uint4 sm[2048];
  const int tid = threadIdx.x;
  const int ty = blockIdx.y;
  const int bm = blockIdx.x;
  const float* X = (ty == 0) ? xq : (ty == 1) ? xk : xv;
  const bf16_t* W = WtAll + (size_t)ty * 131072;
  const int lane = tid & 63;
  const int w = tid >> 6;
  const int l31 = lane & 31, h = lane >> 5;
  const int swl = (l31 >> 1) & 3;

  f32x16 acc[4];
#pragma unroll
  for (int nf = 0; nf < 4; ++nf)
#pragma unroll
    for (int r = 0; r < 16; ++r) acc[nf][r] = 0.0f;

  const int arow0 = tid >> 3, afs = tid & 7;
  const float* agp = X + (size_t)(bm * 128 + arow0) * 1024 + afs * 4;
  const int wn0 = tid >> 2, wsl = tid & 3;
  const bf16_t* wgp = W + (size_t)wn0 * 1024 + wsl * 8;

  for (int kt = 0; kt < 32; ++kt) {
    const int k0 = kt * 32;
    uint4 av[4];
#pragma unroll
    for (int i = 0; i < 4; ++i) av[i] = *(const uint4*)(agp + (size_t)i * 32 * 1024 + k0);
    uint4 wv2[2];
#pragma unroll
    for (int i = 0; i < 2; ++i) wv2[i] = *(const uint4*)(wgp + (size_t)i * 64 * 1024 + k0);
    __syncthreads();
#pragma unroll
    for (int i = 0; i < 4; ++i) {
      int row = arow0 + 32 * i;
      float4 f = __builtin_bit_cast(float4, av[i]);
      bf16x4v bv; bv[0] = (bf16_t)f.x; bv[1] = (bf16_t)f.y; bv[2] = (bf16_t)f.z; bv[3] = (bf16_t)f.w;
      int byt = row * 64 + (((afs >> 1) ^ ((row >> 1) & 3)) << 4) + (afs & 1) * 8;
      *(uint2*)((char*)sm + byt) = __builtin_bit_cast(uint2, bv);
    }
#pragma unroll
    for (int i = 0; i < 2; ++i) {
      int n = wn0 + 64 * i;
      int byt = 8192 + n * 64 + ((wsl ^ ((n >> 1) & 3)) << 4);
      *(uint4*)((char*)sm + byt) = wv2[i];
    }
    __syncthreads();
#pragma unroll
    for (int ks = 0; ks < 2; ++ks) {
      const int so = ((2 * ks + h) ^ swl) << 4;
      bf16x8 af = *(const bf16x8*)((const char*)sm + (w * 32 + l31) * 64 + so);
#pragma unroll
      for (int nf = 0; nf < 4; ++nf) {
        bf16x8 wf = *(const bf16x8*)((const char*)sm + 8192 + (nf * 32 + l31) * 64 + so);
        acc[nf] = mfma32(af, wf, acc[nf]);
      }
    }
  }

  const int mbase = bm * 128 + w * 32;
  if (ty < 2) {
    bf16_t* O = (ty == 0) ? Qp : Kp;
#pragma unroll
    for (int nf = 0; nf < 4; ++nf)
#pragma unroll
      for (int r = 0; r < 16; ++r) {
        int rowD = (r & 3) + 8 * (r >> 2) + 4 * h;
        O[(size_t)(mbase + rowD) * 128 + nf * 32 + l31] = (bf16_t)acc[nf][r];
      }
  } else {
    __syncthreads();
#pragma unroll
    for (int nf = 0; nf < 4; ++nf)
#pragma unroll
      for (int rg = 0; rg < 4; ++rg) {
        int n = nf * 32 + l31;
        bf16x4v bv;
#pragma unroll
        for (int j = 0; j < 4; ++j) bv[j] = (bf16_t)acc[nf][rg * 4 + j];
        int byt = n * 256 + (((4 * w + rg) ^ (n & 7)) << 4) + 8 * h;
        *(uint2*)((char*)sm + byt) = __builtin_bit_cast(uint2, bv);
      }
    __syncthreads();
    const int bb = bm >> 5;
    const int r0v = (bm & 31) * 128;
#pragma unroll
    for (int i = 0; i < 8; ++i) {
      int c = tid + 256 * i;
      int n = c >> 4, sl = c & 15;
      uint4 vv = *(const uint4*)((const char*)sm + n * 256 + ((sl ^ (n & 7)) << 4));
      *(uint4*)(Vt + (size_t)(bb * 128 + n) * 4096 + r0v + sl * 8) = vv;
    }
  }
}

// Flash attention. 128 threads (2 waves), QBLK=64, KVBLK=64, split-KV by SPLIT.
// grid.x = 512*SPLIT: b = bid&7 (XCD affinity), qt = (bid>>3)%64, s = (bid>>3)/64.
template <int SPLIT>
__global__ __launch_bounds__(128, 2) void attn_kernel(
    const bf16_t* __restrict__ Qp, const bf16_t* __restrict__ Kp,
    const bf16_t* __restrict__ Vt, float* __restrict__ out,
    float* __restrict__ Opart, float* __restrict__ Mpart, float* __restrict__ Lpart) {
  __shared__ uint4 sm[2560];  // K [0,16K), V [16K,32K), P per-wave [32K,40K)
  const int tid = threadIdx.x;
  const int lane = tid & 63, w = tid >> 6;
  const int l31 = lane & 31, h = lane >> 5;
  const int bid = blockIdx.x;
  const int b = bid & 7;
  const int qt = (bid >> 3) & 63;
  const int s = (bid >> 3) >> 6;
  const int qbase = qt * 64 + w * 32;
  const int NT = 64 / SPLIT;
  const float CEXP = CEXP_CONST;
  const int ksw0 = (l31 ^ (l31 >> 3)) & 7;

  // Q fragments (B-operand of swapped QK^T): lane holds q-row l31, d = db*16+h*8..+8
  bf16x8 qf[8];
  const bf16_t* qrow = Qp + (size_t)(b * 4096 + qbase + l31) * 128 + h * 8;
#pragma unroll
  for (int db = 0; db < 8; ++db) qf[db] = *(const bf16x8*)(qrow + db * 16);

  const char* kp = (const char*)Kp + (size_t)b * 1048576 + (tid >> 4) * 256 + (tid & 15) * 16 +
                   (size_t)s * NT * 16384;
  const char* vp = (const char*)Vt + (size_t)b * 1048576 + (tid >> 3) * 8192 + (tid & 7) * 16 +
                   (size_t)s * NT * 128;
  const int pbase = 32768 + w * 4096 + l31 * 128;

  f32x16 oacc[4];
#pragma unroll
  for (int nf = 0; nf < 4; ++nf)
#pragma unroll
    for (int r = 0; r < 16; ++r) oacc[nf][r] = 0.0f;
  float m_run = -3.0e38f, lacc = 0.0f;

  // prologue: load first tile into regs
  uint4 kv[8], vv[8];
#pragma unroll
  for (int i = 0; i < 8; ++i) kv[i] = *(const uint4*)(kp + i * 2048);
#pragma unroll
  for (int i = 0; i < 8; ++i) vv[i] = *(const uint4*)(vp + (size_t)i * 131072);

  for (int t = 0; t < NT; ++t) {
    // ---- write staged regs -> swizzled LDS ----
    __syncthreads();
#pragma unroll
    for (int i = 0; i < 8; ++i) {
      int r = (tid >> 4) + 8 * i;
      int byt = r * 256 + (((tid & 15) ^ ((r ^ (r >> 3)) & 7)) << 4);
      *(uint4*)((char*)sm + byt) = kv[i];
    }
#pragma unroll
    for (int i = 0; i < 8; ++i) {
      int r = (tid >> 3) + 16 * i;
      int byt = 16384 + r * 128 + (((tid & 7) ^ ((r ^ (r >> 3)) & 7)) << 4);
      *(uint4*)((char*)sm + byt) = vv[i];
    }
    __syncthreads();

    // ---- S^T = mfma(K, Q) ----
    f32x16 s0, s1;
#pragma unroll
    for (int i = 0; i < 16; ++i) { s0[i] = 0.0f; s1[i] = 0.0f; }
    __builtin_amdgcn_s_setprio(1);
#pragma unroll
    for (int db = 0; db < 8; ++db) {
      const int q = 2 * db + h;
      bf16x8 k0 = *(const bf16x8*)((const char*)sm + l31 * 256 + ((q ^ ksw0) << 4));
      bf16x8 k1 = *(const bf16x8*)((const char*)sm + (32 + l31) * 256 + ((q ^ ksw0 ^ 4) << 4));
      s0 = mfma32(k0, qf[db], s0);
      s1 = mfma32(k1, qf[db], s1);
    }
    __builtin_amdgcn_s_setprio(0);

    // ---- online softmax ----
    float tmax = fmaxf(s0[0], s1[0]);
#pragma unroll
    for (int i = 1; i < 16; ++i) tmax = fmaxf(tmax, fmaxf(s0[i], s1[i]));
    tmax = fmaxf(tmax, __shfl_xor(tmax, 32));
    if (__any(tmax > m_run + 62.0f)) {  // defer-max: p bounded by 2^7.9
      float mnew = fmaxf(m_run, tmax);
      float fac = exp2f((m_run - mnew) * CEXP);
      m_run = mnew;
      lacc *= fac;
#pragma unroll
      for (int r = 0; r < 16; ++r) {
        float fr = __shfl(fac, (r & 3) + 8 * (r >> 2) + 4 * h);
#pragma unroll
        for (int nf = 0; nf < 4; ++nf) oacc[nf][r] *= fr;
      }
    }
    const float mc = m_run * CEXP;
#pragma unroll
    for (int i = 0; i < 16; ++i) s0[i] = exp2f(fmaf(s0[i], CEXP, -mc));
#pragma unroll
    for (int i = 0; i < 16; ++i) s1[i] = exp2f(fmaf(s1[i], CEXP, -mc));
    float a0 = 0.f, a1 = 0.f, a2 = 0.f, a3 = 0.f;
#pragma unroll
    for (int i = 0; i < 16; i += 4) {
      a0 += s0[i] + s1[i];         a1 += s0[i + 1] + s1[i + 1];
      a2 += s0[i + 2] + s1[i + 2]; a3 += s0[i + 3] + s1[i + 3];
    }
    lacc += (a0 + a1) + (a2 + a3);

    // ---- P -> bf16 -> wave-private swizzled LDS ----
#pragma unroll
    for (int rg = 0; rg < 4; ++rg) {
      bf16x4v p0, p1;
#pragma unroll
      for (int j = 0; j < 4; ++j) { p0[j] = (bf16_t)s0[rg * 4 + j]; p1[j] = (bf16_t)s1[rg * 4 + j]; }
      *(uint2*)((char*)sm + pbase + ((rg ^ ksw0) << 4) + 8 * h) = __builtin_bit_cast(uint2, p0);
      *(uint2*)((char*)sm + pbase + (((4 + rg) ^ ksw0) << 4) + 8 * h) = __builtin_bit_cast(uint2, p1);
    }
    asm volatile("" ::: "memory");

    // ---- prefetch next tile (latency hides under PV) ----
    if (t + 1 < NT) {
      kp += 16384; vp += 128;
#pragma unroll
      for (int i = 0; i < 8; ++i) kv[i] = *(const uint4*)(kp + i * 2048);
#pragma unroll
      for (int i = 0; i < 8; ++i) vv[i] = *(const uint4*)(vp + (size_t)i * 131072);
    }

    // ---- PV: out += P[32q x 64j] @ V[64j x 128n] ----
    __builtin_amdgcn_s_setprio(1);
#pragma unroll
    for (int js = 0; js < 4; ++js) {
      const int q = 2 * js + h;
      bf16x8 pf = *(const bf16x8*)((const char*)sm + pbase + ((q ^ ksw0) << 4));
#pragma unroll
      for (int nf = 0; nf < 4; ++nf) {
        int row = nf * 32 + l31;
        int vsw = (l31 & 7) ^ ((4 * nf + (l31 >> 3)) & 7);
        bf16x8 vf = *(const bf16x8*)((const char*)sm + 16384 + row * 128 + ((q ^ vsw) << 4));
        oacc[nf] = mfma32(pf, vf, oacc[nf]);
      }
    }
    __builtin_amdgcn_s_setprio(0);
  }

  lacc += __shfl_xor(lacc, 32);
  if (SPLIT == 1) {
    const float inv = 1.0f / lacc;
    float* ob = out + (size_t)(b * 4096 + qbase) * 128;
#pragma unroll
    for (int r = 0; r < 16; ++r) {
      const int rowD = (r & 3) + 8 * (r >> 2) + 4 * h;
      float ir = __shfl(inv, rowD);
#pragma unroll
      for (int nf = 0; nf < 4; ++nf)
        ob[(size_t)rowD * 128 + nf * 32 + l31] = oacc[nf][r] * ir;
    }
  } else {
    const int pb = s * 512 + b * 64 + qt;
    if (lane < 32) {
      Mpart[pb * 64 + w * 32 + l31] = m_run;
      Lpart[pb * 64 + w * 32 + l31] = lacc;
    }
    float* ob = Opart + ((size_t)pb * 64 + w * 32) * 128;
#pragma unroll
    for (int r = 0; r < 16; ++r) {
      const int rowD = (r & 3) + 8 * (r >> 2) + 4 * h;
#pragma unroll
      for (int nf = 0; nf < 4; ++nf)
        ob[(size_t)rowD * 128 + nf * 32 + l31] = oacc[nf][r];
    }
  }
}

// Combine 2 split partials. grid 4096 x 256: 8 rows/block, 32 lanes/row (float4).
__global__ __launch_bounds__(256) void combine_kernel(
    const float* __restrict__ Opart, const float* __restrict__ Mpart,
    const float* __restrict__ Lpart, float* __restrict__ out) {
  const int g = blockIdx.x * 8 + (threadIdx.x >> 5);  // global q-row, 0..32767
  const int lane32 = threadIdx.x & 31;
  const int bqt = g >> 6;       // b*64+qt, 0..511
  const int row = g & 63;
  const int i0 = bqt * 64 + row;
  const int i1 = (512 + bqt) * 64 + row;
  const float m0 = Mpart[i0], m1 = Mpart[i1];
  const float l0 = Lpart[i0], l1 = Lpart[i1];
  const float m = fmaxf(m0, m1);
  const float w0 = exp2f((m0 - m) * CEXP_CONST);
  const float w1 = exp2f((m1 - m) * CEXP_CONST);
  const float inv = 1.0f / (w0 * l0 + w1 * l1);
  const float4 o0 = *(const float4*)(Opart + (size_t)i0 * 128 + lane32 * 4);
  const float4 o1 = *(const float4*)(Opart + (size_t)i1 * 128 + lane32 * 4);
  float4 o;
  o.x = (w0 * o0.x + w1 * o1.x) * inv;
  o.y = (w0 * o0.y + w1 * o1.y) * inv;
  o.z = (w0 * o0.z + w1 * o1.z) * inv;
  o.w = (w0 * o0.w + w1 * o1.w) * inv;
  *(float4*)(out + (size_t)g * 128 + lane32 * 4) = o;
}

extern "C" void kernel_launch(void* const* d_in, const int* in_sizes, int n_in,
                              void* d_out, int out_size, void* d_ws, size_t ws_size,
                              hipStream_t stream) {
  const float* q  = (const float*)d_in[0];
  const float* k  = (const float*)d_in[1];
  const float* v  = (const float*)d_in[2];
  const float* Wq = (const float*)d_in[3];
  const float* Wk = (const float*)d_in[4];
  const float* Wv = (const float*)d_in[5];
  float* out = (float*)d_out;
  char* ws = (char*)d_ws;
  bf16_t* Wt = (bf16_t*)(ws);
  bf16_t* Qp = (bf16_t*)(ws + (size_t)(1u << 20));
  bf16_t* Kp = (bf16_t*)(ws + (size_t)(9u << 20));
  bf16_t* Vt = (bf16_t*)(ws + (size_t)(17u << 20));
  float* Opart = (float*)(ws + (size_t)(32u << 20));
  float* Mpart = (float*)(ws + (size_t)(64u << 20));
  float* Lpart = (float*)(ws + (size_t)(64u << 20) + (256u << 10));

  hipLaunchKernelGGL(wt_kernel, dim3(1536), dim3(256), 0, stream, Wq, Wk, Wv, Wt);
  hipLaunchKernelGGL(proj_kernel, dim3(256, 3), dim3(256), 0, stream, q, k, v, Wt, Qp, Kp, Vt);

  if (ws_size >= ((size_t)65 << 20)) {
    hipLaunchKernelGGL((attn_kernel<2>), dim3(1024), dim3(128), 0, stream,
                       Qp, Kp, Vt, out, Opart, Mpart, Lpart);
    hipLaunchKernelGGL(combine_kernel, dim3(4096), dim3(256), 0, stream,
                       Opart, Mpart, Lpart, out);
  } else {
    hipLaunchKernelGGL((attn_kernel<1>), dim3(512), dim3(128), 0, stream,
                       Qp, Kp, Vt, out, Opart, Mpart, Lpart);
  }
}

// Round 3
// 265.298 us; speedup vs baseline: 1.8560x; 1.8560x over previous
//
#include <hip/hip_runtime.h>
#include <cstdint>
#include <cstddef>

typedef __bf16 bf16_t;
typedef __bf16 bf16x8 __attribute__((ext_vector_type(8)));
typedef __bf16 bf16x4v __attribute__((ext_vector_type(4)));
typedef float f32x16 __attribute__((ext_vector_type(16)));

static __device__ __forceinline__ f32x16 mfma32(bf16x8 a, bf16x8 b, f32x16 c) {
  return __builtin_amdgcn_mfma_f32_32x32x16_bf16(a, b, c, 0, 0, 0);
}

// Direct global->LDS DMA, 16B per lane. LDS dest is wave-uniform base + lane*16;
// global src is per-lane (swizzle baked into the gather address).
static __device__ __forceinline__ void gld_lds16(const void* g, void* l) {
  __builtin_amdgcn_global_load_lds(
      (const __attribute__((address_space(1))) unsigned int*)g,
      (__attribute__((address_space(3))) unsigned int*)l, 16, 0, 0);
}

#define CEXP_CONST 0.12754582f  // (1/sqrt(128)) * log2(e)

// ---------------------------------------------------------------------------
// Workspace layout (bytes):
//   [0, 768K)        Wt    bf16 [3][128][1024]
//   [1M, 9M)         Qp    bf16 [8][4096][128]
//   [9M, 17M)        Kp    bf16 [8][4096][128]
//   [17M, 25M)       Vt    bf16 [8][128][4096]
//   [32M, 64M)       Opart f32  [2*256][128][128]
//   [64M, +256K)     Mpart f32  [2*256*128]
//   [64M+256K,+256K) Lpart f32  [2*256*128]
// ---------------------------------------------------------------------------

__global__ void wt_kernel(const float* __restrict__ Wq, const float* __restrict__ Wk,
                          const float* __restrict__ Wv, bf16_t* __restrict__ Wt) {
  int t = blockIdx.x * 256 + threadIdx.x;
  int tensor = t >> 17;
  int r = t & 131071;
  int kk = r >> 7, n = r & 127;
  const float* W = tensor == 0 ? Wq : (tensor == 1 ? Wk : Wv);
  Wt[(size_t)tensor * 131072 + (size_t)n * 1024 + kk] = (bf16_t)W[(size_t)kk * 128 + n];
}

// X[32768,1024]f32 @ W[1024,128] -> bf16. ty: 0=Q, 1=K (row-major), 2=V (transposed out).
__global__ __launch_bounds__(256, 2) void proj_kernel(
    const float* __restrict__ xq, const float* __restrict__ xk, const float* __restrict__ xv,
    const bf16_t* __restrict__ WtAll,
    bf16_t* __restrict__ Qp, bf16_t* __restrict__ Kp, bf16_t* __restrict__ Vt) {
  __shared__ uint4 sm[2048];
  const int tid = threadIdx.x;
  const int ty = blockIdx.y;
  const int bm = blockIdx.x;
  const float* X = (ty == 0) ? xq : (ty == 1) ? xk : xv;
  const bf16_t* W = WtAll + (size_t)ty * 131072;
  const int lane = tid & 63;
  const int w = tid >> 6;
  const int l31 = lane & 31, h = lane >> 5;
  const int swl = (l31 >> 1) & 3;

  f32x16 acc[4];
#pragma unroll
  for (int nf = 0; nf < 4; ++nf)
#pragma unroll
    for (int r = 0; r < 16; ++r) acc[nf][r] = 0.0f;

  const int arow0 = tid >> 3, afs = tid & 7;
  const float* agp = X + (size_t)(bm * 128 + arow0) * 1024 + afs * 4;
  const int wn0 = tid >> 2, wsl = tid & 3;
  const bf16_t* wgp = W + (size_t)wn0 * 1024 + wsl * 8;

  for (int kt = 0; kt < 32; ++kt) {
    const int k0 = kt * 32;
    uint4 av[4];
#pragma unroll
    for (int i = 0; i < 4; ++i) av[i] = *(const uint4*)(agp + (size_t)i * 32 * 1024 + k0);
    uint4 wv2[2];
#pragma unroll
    for (int i = 0; i < 2; ++i) wv2[i] = *(const uint4*)(wgp + (size_t)i * 64 * 1024 + k0);
    __syncthreads();
#pragma unroll
    for (int i = 0; i < 4; ++i) {
      int row = arow0 + 32 * i;
      float4 f = __builtin_bit_cast(float4, av[i]);
      bf16x4v bv; bv[0] = (bf16_t)f.x; bv[1] = (bf16_t)f.y; bv[2] = (bf16_t)f.z; bv[3] = (bf16_t)f.w;
      int byt = row * 64 + (((afs >> 1) ^ ((row >> 1) & 3)) << 4) + (afs & 1) * 8;
      *(uint2*)((char*)sm + byt) = __builtin_bit_cast(uint2, bv);
    }
#pragma unroll
    for (int i = 0; i < 2; ++i) {
      int n = wn0 + 64 * i;
      int byt = 8192 + n * 64 + ((wsl ^ ((n >> 1) & 3)) << 4);
      *(uint4*)((char*)sm + byt) = wv2[i];
    }
    __syncthreads();
#pragma unroll
    for (int ks = 0; ks < 2; ++ks) {
      const int so = ((2 * ks + h) ^ swl) << 4;
      bf16x8 af = *(const bf16x8*)((const char*)sm + (w * 32 + l31) * 64 + so);
#pragma unroll
      for (int nf = 0; nf < 4; ++nf) {
        bf16x8 wf = *(const bf16x8*)((const char*)sm + 8192 + (nf * 32 + l31) * 64 + so);
        acc[nf] = mfma32(af, wf, acc[nf]);
      }
    }
  }

  const int mbase = bm * 128 + w * 32;
  if (ty < 2) {
    bf16_t* O = (ty == 0) ? Qp : Kp;
#pragma unroll
    for (int nf = 0; nf < 4; ++nf)
#pragma unroll
      for (int r = 0; r < 16; ++r) {
        int rowD = (r & 3) + 8 * (r >> 2) + 4 * h;
        O[(size_t)(mbase + rowD) * 128 + nf * 32 + l31] = (bf16_t)acc[nf][r];
      }
  } else {
    __syncthreads();
#pragma unroll
    for (int nf = 0; nf < 4; ++nf)
#pragma unroll
      for (int rg = 0; rg < 4; ++rg) {
        int n = nf * 32 + l31;
        bf16x4v bv;
#pragma unroll
        for (int j = 0; j < 4; ++j) bv[j] = (bf16_t)acc[nf][rg * 4 + j];
        int byt = n * 256 + (((4 * w + rg) ^ (n & 7)) << 4) + 8 * h;
        *(uint2*)((char*)sm + byt) = __builtin_bit_cast(uint2, bv);
      }
    __syncthreads();
    const int bb = bm >> 5;
    const int r0v = (bm & 31) * 128;
#pragma unroll
    for (int i = 0; i < 8; ++i) {
      int c = tid + 256 * i;
      int n = c >> 4, sl = c & 15;
      uint4 vv = *(const uint4*)((const char*)sm + n * 256 + ((sl ^ (n & 7)) << 4));
      *(uint4*)(Vt + (size_t)(bb * 128 + n) * 4096 + r0v + sl * 8) = vv;
    }
  }
}

// Build PV A-fragment (j = B0-half of one f32x16 S block, 16 j's) in-register:
// 4x v_cvt_pk_bf16_f32 + 4x shfl_xor(32) + selects. No LDS.
template <int B0>
static __device__ __forceinline__ bf16x8 build_pf(const f32x16& s, int h) {
  unsigned c0, c1, c2, c3;
  asm("v_cvt_pk_bf16_f32 %0, %1, %2" : "=v"(c0) : "v"(s[B0 + 0]), "v"(s[B0 + 1]));
  asm("v_cvt_pk_bf16_f32 %0, %1, %2" : "=v"(c1) : "v"(s[B0 + 2]), "v"(s[B0 + 3]));
  asm("v_cvt_pk_bf16_f32 %0, %1, %2" : "=v"(c2) : "v"(s[B0 + 4]), "v"(s[B0 + 5]));
  asm("v_cvt_pk_bf16_f32 %0, %1, %2" : "=v"(c3) : "v"(s[B0 + 6]), "v"(s[B0 + 7]));
  unsigned x0 = (unsigned)__shfl_xor((int)c0, 32);
  unsigned x1 = (unsigned)__shfl_xor((int)c1, 32);
  unsigned x2 = (unsigned)__shfl_xor((int)c2, 32);
  unsigned x3 = (unsigned)__shfl_xor((int)c3, 32);
  uint4 u;
  u.x = h ? x2 : c0;
  u.y = h ? x3 : c1;
  u.z = h ? c2 : x0;
  u.w = h ? c3 : x1;
  return __builtin_bit_cast(bf16x8, u);
}

// Flash attention. 256 threads (4 waves), QBLK=128 (32 q-rows/wave), KVBLK=64.
// K/V double-buffered in LDS via global_load_lds with gather-side swizzle;
// counted vmcnt(8) pipeline (never 0 in main loop).
// grid.x = 256*SPLIT: b = bid&7 (XCD affinity), qt = (bid>>3)&31, s = bid>>8.
template <int SPLIT>
__global__ __launch_bounds__(256, 2) void attn_kernel(
    const bf16_t* __restrict__ Qp, const bf16_t* __restrict__ Kp,
    const bf16_t* __restrict__ Vt, float* __restrict__ out,
    float* __restrict__ Opart, float* __restrict__ Mpart, float* __restrict__ Lpart) {
  __shared__ __align__(16) char smc[65536];  // 2 x (K 16K | V 16K)
  const int tid = threadIdx.x;
  const int lane = tid & 63, w = tid >> 6;
  const int l31 = lane & 31, h = lane >> 5;
  const int bid = blockIdx.x;
  const int b = bid & 7;
  const int qt = (bid >> 3) & 31;
  const int s = bid >> 8;
  const int NT = 64 / SPLIT;
  const float CEXP = CEXP_CONST;
  const int qbase = qt * 128 + w * 32;
  const int sw0 = (l31 ^ (l31 >> 3)) & 7;  // K-row swizzle for row l31
  const int sw1 = sw0 ^ 4;                 // for row l31+32

  // Q fragments: lane holds q-row l31, d = db*16 + h*8 + 0..8
  bf16x8 qf[8];
  const bf16_t* qrow = Qp + (size_t)(b * 4096 + qbase + l31) * 128 + h * 8;
#pragma unroll
  for (int db = 0; db < 8; ++db) qf[db] = *(const bf16x8*)(qrow + db * 16);

  // V-row swizzle for rows d = nf*32 + l31
  int swv[4];
#pragma unroll
  for (int nf = 0; nf < 4; ++nf) swv[nf] = (l31 & 7) ^ ((4 * nf + (l31 >> 3)) & 7);

  // Gather offsets (swizzle on the global side; LDS dest linear).
  // K: wave w stages rows 16w..16w+15 (4 chunks of 4 rows x 16 slots).
  // V: wave w stages d-rows 32w..32w+31 (4 chunks of 8 rows x 8 slots).
  const int rl = lane >> 4, slK = lane & 15;
  const int dl = lane >> 3, slV = lane & 7;
  int koff[4], voff[4];
#pragma unroll
  for (int i = 0; i < 4; ++i) {
    int r = w * 16 + i * 4 + rl;
    int swr = (r ^ (r >> 3)) & 7;
    koff[i] = r * 256 + (((slK & 8) | ((slK & 7) ^ swr)) << 4);
    int d = w * 32 + i * 8 + dl;
    int swd = (d ^ (d >> 3)) & 7;
    voff[i] = d * 8192 + ((slV ^ swd) << 4);
  }
  const char* kpb = (const char*)Kp + (size_t)b * 1048576 + (size_t)s * NT * 16384;
  const char* vpb = (const char*)Vt + (size_t)b * 1048576 + (size_t)s * NT * 128;

  f32x16 oacc[4];
#pragma unroll
  for (int nf = 0; nf < 4; ++nf)
#pragma unroll
    for (int r = 0; r < 16; ++r) oacc[nf][r] = 0.0f;
  float m_run = -3.0e38f, lacc = 0.0f;

  auto stage = [&](int tt, int bufb) {
    const char* kb = kpb + (size_t)tt * 16384;
    const char* vb = vpb + (size_t)tt * 128;
    char* lk = smc + bufb + w * 4096;
    char* lv = smc + bufb + 16384 + w * 4096;
#pragma unroll
    for (int i = 0; i < 4; ++i) {
      gld_lds16(kb + koff[i], lk + i * 1024);
      gld_lds16(vb + voff[i], lv + i * 1024);
    }
  };

  stage(0, 0);
  stage(1, 32768);

  for (int t = 0; t < NT; ++t) {
    asm volatile("s_waitcnt vmcnt(8)" ::: "memory");  // tile t landed; t+1 in flight
    __builtin_amdgcn_s_barrier();
    const char* kb = smc + (t & 1) * 32768;
    const char* vb = kb + 16384;

    // ---- S^T = mfma(K, Q): lane owns q-row l31 ----
    f32x16 s0, s1;
#pragma unroll
    for (int i = 0; i < 16; ++i) { s0[i] = 0.0f; s1[i] = 0.0f; }
    __builtin_amdgcn_s_setprio(1);
#pragma unroll
    for (int db = 0; db < 8; ++db) {
      const int q = 2 * db + h;
      bf16x8 k0 = *(const bf16x8*)(kb + l31 * 256 + (((q & 8) | ((q & 7) ^ sw0)) << 4));
      bf16x8 k1 = *(const bf16x8*)(kb + (32 + l31) * 256 + (((q & 8) | ((q & 7) ^ sw1)) << 4));
      s0 = mfma32(k0, qf[db], s0);
      s1 = mfma32(k1, qf[db], s1);
    }
    __builtin_amdgcn_s_setprio(0);

    // ---- online softmax (raw logits; scale folded into exp2) ----
    float tmax = fmaxf(s0[0], s1[0]);
#pragma unroll
    for (int i = 1; i < 16; ++i) tmax = fmaxf(tmax, fmaxf(s0[i], s1[i]));
    tmax = fmaxf(tmax, __shfl_xor(tmax, 32));
    if (__any(tmax > m_run + 62.0f)) {  // defer-max: p bounded by 2^7.9
      float mnew = fmaxf(m_run, tmax);
      float fac = exp2f((m_run - mnew) * CEXP);
      m_run = mnew;
      lacc *= fac;
#pragma unroll
      for (int r = 0; r < 16; ++r) {
        float fr = __shfl(fac, (r & 3) + 8 * (r >> 2) + 4 * h);
#pragma unroll
        for (int nf = 0; nf < 4; ++nf) oacc[nf][r] *= fr;
      }
    }
    const float mc = m_run * CEXP;
#pragma unroll
    for (int i = 0; i < 16; ++i) s0[i] = exp2f(fmaf(s0[i], CEXP, -mc));
#pragma unroll
    for (int i = 0; i < 16; ++i) s1[i] = exp2f(fmaf(s1[i], CEXP, -mc));
    float a0 = 0.f, a1 = 0.f, a2 = 0.f, a3 = 0.f;
#pragma unroll
    for (int i = 0; i < 16; i += 4) {
      a0 += s0[i] + s1[i];         a1 += s0[i + 1] + s1[i + 1];
      a2 += s0[i + 2] + s1[i + 2]; a3 += s0[i + 3] + s1[i + 3];
    }
    lacc += (a0 + a1) + (a2 + a3);

    // ---- PV: oacc += P[32q x 64j] @ V[64j x 128d], P built in-register ----
    __builtin_amdgcn_s_setprio(1);
    {
      bf16x8 pf = build_pf<0>(s0, h);
#pragma unroll
      for (int nf = 0; nf < 4; ++nf) {
        bf16x8 vf = *(const bf16x8*)(vb + (nf * 32 + l31) * 128 + (((0 + h) ^ swv[nf]) << 4));
        oacc[nf] = mfma32(pf, vf, oacc[nf]);
      }
    }
    {
      bf16x8 pf = build_pf<8>(s0, h);
#pragma unroll
      for (int nf = 0; nf < 4; ++nf) {
        bf16x8 vf = *(const bf16x8*)(vb + (nf * 32 + l31) * 128 + (((2 + h) ^ swv[nf]) << 4));
        oacc[nf] = mfma32(pf, vf, oacc[nf]);
      }
    }
    {
      bf16x8 pf = build_pf<0>(s1, h);
#pragma unroll
      for (int nf = 0; nf < 4; ++nf) {
        bf16x8 vf = *(const bf16x8*)(vb + (nf * 32 + l31) * 128 + (((4 + h) ^ swv[nf]) << 4));
        oacc[nf] = mfma32(pf, vf, oacc[nf]);
      }
    }
    {
      bf16x8 pf = build_pf<8>(s1, h);
#pragma unroll
      for (int nf = 0; nf < 4; ++nf) {
        bf16x8 vf = *(const bf16x8*)(vb + (nf * 32 + l31) * 128 + (((6 + h) ^ swv[nf]) << 4));
        oacc[nf] = mfma32(pf, vf, oacc[nf]);
      }
    }
    __builtin_amdgcn_s_setprio(0);

    __builtin_amdgcn_s_barrier();  // all waves done reading buf[t&1]
    stage((t + 2) & (NT - 1), (t & 1) * 32768);  // wrap keeps vmcnt count uniform
  }
  asm volatile("s_waitcnt vmcnt(0)" ::: "memory");  // drain wrap loads

  lacc += __shfl_xor(lacc, 32);
  if (SPLIT == 1) {
    const float inv = 1.0f / lacc;
    float* ob = out + (size_t)(b * 4096 + qbase) * 128;
#pragma unroll
    for (int r = 0; r < 16; ++r) {
      const int rowD = (r & 3) + 8 * (r >> 2) + 4 * h;
      float ir = __shfl(inv, rowD);
#pragma unroll
      for (int nf = 0; nf < 4; ++nf)
        ob[(size_t)rowD * 128 + nf * 32 + l31] = oacc[nf][r] * ir;
    }
  } else {
    const int pb = s * 256 + b * 32 + qt;
    if (lane < 32) {
      Mpart[pb * 128 + w * 32 + l31] = m_run;
      Lpart[pb * 128 + w * 32 + l31] = lacc;
    }
    float* ob = Opart + ((size_t)pb * 128 + w * 32) * 128;
#pragma unroll
    for (int r = 0; r < 16; ++r) {
      const int rowD = (r & 3) + 8 * (r >> 2) + 4 * h;
#pragma unroll
      for (int nf = 0; nf < 4; ++nf)
        ob[(size_t)rowD * 128 + nf * 32 + l31] = oacc[nf][r];
    }
  }
}

// Combine 2 split partials. grid 4096 x 256: 8 rows/block, 32 lanes/row (float4).
__global__ __launch_bounds__(256) void combine_kernel(
    const float* __restrict__ Opart, const float* __restrict__ Mpart,
    const float* __restrict__ Lpart, float* __restrict__ out) {
  const int g = blockIdx.x * 8 + (threadIdx.x >> 5);  // global q-row, 0..32767
  const int lane32 = threadIdx.x & 31;
  const int b = g >> 12;
  const int pos = g & 4095;
  const int qt = pos >> 7;
  const int row = pos & 127;
  const int i0 = (b * 32 + qt) * 128 + row;
  const int i1 = (256 + b * 32 + qt) * 128 + row;
  const float m0 = Mpart[i0], m1 = Mpart[i1];
  const float l0 = Lpart[i0], l1 = Lpart[i1];
  const float m = fmaxf(m0, m1);
  const float w0 = exp2f((m0 - m) * CEXP_CONST);
  const float w1 = exp2f((m1 - m) * CEXP_CONST);
  const float inv = 1.0f / (w0 * l0 + w1 * l1);
  const float4 o0 = *(const float4*)(Opart + (size_t)i0 * 128 + lane32 * 4);
  const float4 o1 = *(const float4*)(Opart + (size_t)i1 * 128 + lane32 * 4);
  float4 o;
  o.x = (w0 * o0.x + w1 * o1.x) * inv;
  o.y = (w0 * o0.y + w1 * o1.y) * inv;
  o.z = (w0 * o0.z + w1 * o1.z) * inv;
  o.w = (w0 * o0.w + w1 * o1.w) * inv;
  *(float4*)(out + (size_t)g * 128 + lane32 * 4) = o;
}

extern "C" void kernel_launch(void* const* d_in, const int* in_sizes, int n_in,
                              void* d_out, int out_size, void* d_ws, size_t ws_size,
                              hipStream_t stream) {
  const float* q  = (const float*)d_in[0];
  const float* k  = (const float*)d_in[1];
  const float* v  = (const float*)d_in[2];
  const float* Wq = (const float*)d_in[3];
  const float* Wk = (const float*)d_in[4];
  const float* Wv = (const float*)d_in[5];
  float* out = (float*)d_out;
  char* ws = (char*)d_ws;
  bf16_t* Wt = (bf16_t*)(ws);
  bf16_t* Qp = (bf16_t*)(ws + (size_t)(1u << 20));
  bf16_t* Kp = (bf16_t*)(ws + (size_t)(9u << 20));
  bf16_t* Vt = (bf16_t*)(ws + (size_t)(17u << 20));
  float* Opart = (float*)(ws + (size_t)(32u << 20));
  float* Mpart = (float*)(ws + (size_t)(64u << 20));
  float* Lpart = (float*)(ws + (size_t)(64u << 20) + (256u << 10));

  hipLaunchKernelGGL(wt_kernel, dim3(1536), dim3(256), 0, stream, Wq, Wk, Wv, Wt);
  hipLaunchKernelGGL(proj_kernel, dim3(256, 3), dim3(256), 0, stream, q, k, v, Wt, Qp, Kp, Vt);

  if (ws_size >= ((size_t)65 << 20)) {
    hipLaunchKernelGGL((attn_kernel<2>), dim3(512), dim3(256), 0, stream,
                       Qp, Kp, Vt, out, Opart, Mpart, Lpart);
    hipLaunchKernelGGL(combine_kernel, dim3(4096), dim3(256), 0, stream,
                       Opart, Mpart, Lpart, out);
  } else {
    hipLaunchKernelGGL((attn_kernel<1>), dim3(256), dim3(256), 0, stream,
                       Qp, Kp, Vt, out, Opart, Mpart, Lpart);
  }
}